// Round 1
// baseline (2285.790 us; speedup 1.0000x reference)
//
#include <hip/hip_runtime.h>
#include <stdint.h>

// Problem dims (TabM packed ensemble)
#define BB   4096
#define FF   512
#define HH   1024
#define CC   100
#define KE   32
#define NHIDL 3
#define CPAD 128   // W_out N padded to 128 (rows 100..127 zeroed)

typedef __attribute__((ext_vector_type(8))) short short8;   // 8 x fp16 = 4 VGPRs
typedef __attribute__((ext_vector_type(4))) float float4_t; // MFMA accumulator

// fp32 -> fp16 (RNE via hardware cvt)
__device__ __forceinline__ unsigned short f2h(float f) {
  _Float16 h = (_Float16)f;
  union { _Float16 h; unsigned short u; } cv;
  cv.h = h;
  return cv.u;
}

// async global->LDS, 16B per lane. LDS dest is wave-uniform base + lane*16.
__device__ __forceinline__ void gll16(const void* g, void* l) {
  __builtin_amdgcn_global_load_lds((const __attribute__((address_space(1))) void*)g,
                                   (__attribute__((address_space(3))) void*)l,
                                   16, 0, 0);
}

// ---------------------------------------------------------------------------
// elementwise fp32 -> fp16 convert (x)
__global__ void cvt_f16(const float* __restrict__ in, unsigned short* __restrict__ out, int n4) {
  int i = blockIdx.x * 256 + threadIdx.x;
  if (i < n4) {
    float4 v = ((const float4*)in)[i];
    ushort4 o;
    o.x = f2h(v.x); o.y = f2h(v.y); o.z = f2h(v.z); o.w = f2h(v.w);
    ((ushort4*)out)[i] = o;
  }
}

// ---------------------------------------------------------------------------
// batched transpose + convert: in fp32 [batch][R][C] -> out fp16 [batch][Cpad][R]
// (rows C..Cpad-1 of output zero-filled). R % 32 == 0 required.
__global__ void transpose_cvt(const float* __restrict__ in, unsigned short* __restrict__ out,
                              int R, int C, int Cpad) {
  __shared__ float tile[32][33];
  int b = blockIdx.z;
  const float* ib = in + (size_t)b * R * C;
  unsigned short* ob = out + (size_t)b * Cpad * R;
  int c0 = blockIdx.x * 32, r0 = blockIdx.y * 32;
  int tx = threadIdx.x & 31, ty = threadIdx.x >> 5;
#pragma unroll
  for (int j = 0; j < 4; ++j) {
    int r = r0 + ty + j * 8, c = c0 + tx;
    tile[ty + j * 8][tx] = (c < C) ? ib[(size_t)r * C + c] : 0.0f;
  }
  __syncthreads();
#pragma unroll
  for (int j = 0; j < 4; ++j) {
    int orow = c0 + ty + j * 8, ocol = r0 + tx;
    if (orow < Cpad) ob[(size_t)orow * R + ocol] = f2h(tile[tx][ty + j * 8]);
  }
}

// ---------------------------------------------------------------------------
// Batched GEMM (grid.z = ensemble member k):
//   C[k] = act(A[k] [M x Kd] row-major  @  Bt[k]^T  + bias[k])
// Bt is [Ntile*128][Kd] row-major (N-major transposed weights) so both A and B
// fragments are k-contiguous (ds_read_b128).
// Tile: 128x128 per block, 256 threads = 4 waves in 2x2, each wave 4x4 of
// 16x16x32 MFMA. BK=32 staged via global_load_lds with XOR column-group
// swizzle (2-way bank aliasing only).
template <int RELU, int FINAL>
__global__ __launch_bounds__(256) void gemm_f16(
    const unsigned short* __restrict__ A, long long sAk,
    const unsigned short* __restrict__ Bt, long long sBk,
    const float* __restrict__ bias, int sBiasK,
    unsigned short* __restrict__ Out, long long sOutK,
    float* __restrict__ OutF, int Kd, float scale) {
  const int t = threadIdx.x;
  const int lane = t & 63;
  const int wave = t >> 6;
  const int wm = wave & 1;
  const int wn = wave >> 1;
  const int kz = blockIdx.z;
  const int m0 = blockIdx.y * 128;
  const int n0 = blockIdx.x * 128;

  const unsigned short* Ab = A + (long long)kz * sAk + (long long)m0 * Kd;
  const unsigned short* Bb = Bt + (long long)kz * sBk + (long long)n0 * Kd;

  __shared__ __align__(16) unsigned short smA[128 * 32];
  __shared__ __align__(16) unsigned short smB[128 * 32];

  float4_t acc[4][4];
#pragma unroll
  for (int i = 0; i < 4; ++i)
#pragma unroll
    for (int j = 0; j < 4; ++j) acc[i][j] = (float4_t){0.f, 0.f, 0.f, 0.f};

  // staging assignment: linear 16B slot s = j*256 + t covers tile row s>>2,
  // slot col-group p = s&3 which holds global col-group g = (p - (row>>1)) & 3
  const int lin0 = t, lin1 = t + 256;
  const int row0 = lin0 >> 2, p0 = lin0 & 3;
  const int row1 = lin1 >> 2, p1 = lin1 & 3;
  const int g0 = (p0 - (row0 >> 1)) & 3;
  const int g1 = (p1 - (row1 >> 1)) & 3;
  const unsigned short* ga0 = Ab + (long long)row0 * Kd + g0 * 8;
  const unsigned short* ga1 = Ab + (long long)row1 * Kd + g1 * 8;
  const unsigned short* gb0 = Bb + (long long)row0 * Kd + g0 * 8;
  const unsigned short* gb1 = Bb + (long long)row1 * Kd + g1 * 8;
  unsigned short* la0 = smA + (((unsigned)t & ~63u) << 3);
  unsigned short* la1 = smA + ((256u + ((unsigned)t & ~63u)) << 3);
  unsigned short* lb0 = smB + (((unsigned)t & ~63u) << 3);
  unsigned short* lb1 = smB + ((256u + ((unsigned)t & ~63u)) << 3);

  const int r16 = lane & 15;
  const int q = lane >> 4;
  // fragment LDS offsets (swizzled), invariant across K-steps
  int offA[4], offB[4];
#pragma unroll
  for (int i = 0; i < 4; ++i) {
    int ra = wm * 64 + i * 16 + r16;
    offA[i] = ra * 32 + (((q + (ra >> 1)) & 3) << 3);
    int rb = wn * 64 + i * 16 + r16;
    offB[i] = rb * 32 + (((q + (rb >> 1)) & 3) << 3);
  }

  for (int kt = 0; kt < Kd; kt += 32) {
    gll16(ga0 + kt, la0);
    gll16(ga1 + kt, la1);
    gll16(gb0 + kt, lb0);
    gll16(gb1 + kt, lb1);
    __syncthreads();  // compiler drains vmcnt before s_barrier

    short8 af[4], bf[4];
#pragma unroll
    for (int i = 0; i < 4; ++i) af[i] = *(const short8*)(smA + offA[i]);
#pragma unroll
    for (int i = 0; i < 4; ++i) bf[i] = *(const short8*)(smB + offB[i]);

#pragma unroll
    for (int mi = 0; mi < 4; ++mi)
#pragma unroll
      for (int ni = 0; ni < 4; ++ni)
        acc[mi][ni] = __builtin_amdgcn_mfma_f32_16x16x32_f16(af[mi], bf[ni], acc[mi][ni], 0, 0, 0);

    __syncthreads();  // protect LDS from next iteration's staging
  }

  // epilogue: C/D layout col = lane&15, row = (lane>>4)*4 + reg  [m89-verified]
  const int rbase = q * 4;
  if (FINAL) {
#pragma unroll
    for (int ni = 0; ni < 4; ++ni) {
      int n = wn * 64 + ni * 16 + r16;  // n0 == 0 for final layer
      if (n < CC) {
        float bv = bias[kz * sBiasK + n];
#pragma unroll
        for (int mi = 0; mi < 4; ++mi) {
#pragma unroll
          for (int r = 0; r < 4; ++r) {
            int m = m0 + wm * 64 + mi * 16 + rbase + r;
            atomicAdd(&OutF[(long long)m * CC + n], (acc[mi][ni][r] + bv) * scale);
          }
        }
      }
    }
  } else {
#pragma unroll
    for (int ni = 0; ni < 4; ++ni) {
      int n = n0 + wn * 64 + ni * 16 + r16;
      float bv = bias[kz * sBiasK + n];
#pragma unroll
      for (int mi = 0; mi < 4; ++mi) {
        int m = m0 + wm * 64 + mi * 16 + rbase;
        unsigned short* op = Out + (long long)kz * sOutK + (long long)m * HH + n;
#pragma unroll
        for (int r = 0; r < 4; ++r) {
          float v = acc[mi][ni][r] + bv;
          if (RELU) v = fmaxf(v, 0.f);
          op[(long long)r * HH] = f2h(v);
        }
      }
    }
  }
}

// ---------------------------------------------------------------------------
extern "C" void kernel_launch(void* const* d_in, const int* in_sizes, int n_in,
                              void* d_out, int out_size, void* d_ws, size_t ws_size,
                              hipStream_t stream) {
  (void)in_sizes; (void)n_in; (void)out_size;
  const float* x     = (const float*)d_in[0];
  const float* W_in  = (const float*)d_in[1];
  const float* b_in  = (const float*)d_in[2];
  const float* W_hid = (const float*)d_in[3];
  const float* b_hid = (const float*)d_in[4];
  const float* W_out = (const float*)d_in[5];
  const float* b_out = (const float*)d_in[6];
  float* out = (float*)d_out;

  char* ws = (char*)d_ws;
  size_t off = 0;
  auto alloc = [&](size_t bytes) -> void* {
    void* p = ws + off;
    off += (bytes + 255) & ~(size_t)255;
    return p;
  };
  unsigned short* xb    = (unsigned short*)alloc((size_t)BB * FF * 2);
  unsigned short* WinT  = (unsigned short*)alloc((size_t)KE * HH * FF * 2);
  unsigned short* WhidT = (unsigned short*)alloc((size_t)NHIDL * KE * HH * HH * 2);
  unsigned short* WoutT = (unsigned short*)alloc((size_t)KE * CPAD * HH * 2);
  size_t fixed = off;

  int Bc = BB;  // batch chunk; shrink if workspace is small
  while (Bc > 128 && fixed + 2 * (size_t)KE * Bc * HH * 2 > ws_size) Bc >>= 1;
  unsigned short* h0 = (unsigned short*)alloc((size_t)KE * Bc * HH * 2);
  unsigned short* h1 = (unsigned short*)alloc((size_t)KE * Bc * HH * 2);

  hipMemsetAsync(d_out, 0, (size_t)BB * CC * sizeof(float), stream);

  // conversions / weight transposes (fp32 -> fp16, W stored N-major)
  cvt_f16<<<(BB * FF / 4 + 255) / 256, 256, 0, stream>>>(x, xb, BB * FF / 4);
  transpose_cvt<<<dim3(HH / 32, FF / 32, KE), 256, 0, stream>>>(W_in, WinT, FF, HH, HH);
  transpose_cvt<<<dim3(HH / 32, HH / 32, NHIDL * KE), 256, 0, stream>>>(W_hid, WhidT, HH, HH, HH);
  transpose_cvt<<<dim3(CPAD / 32, HH / 32, KE), 256, 0, stream>>>(W_out, WoutT, HH, CC, CPAD);

  const float scale = 1.0f / (float)KE;
  for (int c0 = 0; c0 < BB; c0 += Bc) {
    // layer 0: [Bc,F] @ [F,H] (A shared across k -> stride 0)
    gemm_f16<1, 0><<<dim3(HH / 128, Bc / 128, KE), 256, 0, stream>>>(
        xb + (size_t)c0 * FF, 0LL, WinT, (long long)HH * FF, b_in, HH,
        h0, (long long)Bc * HH, nullptr, FF, 0.f);
    unsigned short* hin = h0;
    unsigned short* hout = h1;
    for (int l = 0; l < NHIDL; ++l) {
      gemm_f16<1, 0><<<dim3(HH / 128, Bc / 128, KE), 256, 0, stream>>>(
          hin, (long long)Bc * HH, WhidT + (size_t)l * KE * HH * HH, (long long)HH * HH,
          b_hid + (size_t)l * KE * HH, HH, hout, (long long)Bc * HH, nullptr, HH, 0.f);
      unsigned short* tmp = hin; hin = hout; hout = tmp;
    }
    // output layer + mean over k (atomic accumulate, scale = 1/K)
    gemm_f16<0, 1><<<dim3(1, Bc / 128, KE), 256, 0, stream>>>(
        hin, (long long)Bc * HH, WoutT, (long long)CPAD * HH, b_out, CC,
        nullptr, 0LL, out + (size_t)c0 * CC, HH, scale);
  }
}

// Round 2
// 1993.588 us; speedup vs baseline: 1.1466x; 1.1466x over previous
//
#include <hip/hip_runtime.h>
#include <stdint.h>

// Problem dims (TabM packed ensemble)
#define BB   4096
#define FF   512
#define HH   1024
#define CC   100
#define KE   32
#define NHIDL 3
#define CPAD 128   // W_out N padded to 128 (rows 100..127 zeroed)

typedef __attribute__((ext_vector_type(8))) short short8;   // 8 x fp16 = 4 VGPRs
typedef __attribute__((ext_vector_type(4))) float float4_t; // MFMA accumulator

// fp32 -> fp16 (RNE via hardware cvt)
__device__ __forceinline__ unsigned short f2h(float f) {
  _Float16 h = (_Float16)f;
  union { _Float16 h; unsigned short u; } cv;
  cv.h = h;
  return cv.u;
}

// async global->LDS, 16B per lane. LDS dest is wave-uniform base + lane*16.
__device__ __forceinline__ void gll16(const void* g, void* l) {
  __builtin_amdgcn_global_load_lds((const __attribute__((address_space(1))) void*)g,
                                   (__attribute__((address_space(3))) void*)l,
                                   16, 0, 0);
}

// ---------------------------------------------------------------------------
// elementwise fp32 -> fp16 convert (x)
__global__ void cvt_f16(const float* __restrict__ in, unsigned short* __restrict__ out, int n4) {
  int i = blockIdx.x * 256 + threadIdx.x;
  if (i < n4) {
    float4 v = ((const float4*)in)[i];
    ushort4 o;
    o.x = f2h(v.x); o.y = f2h(v.y); o.z = f2h(v.z); o.w = f2h(v.w);
    ((ushort4*)out)[i] = o;
  }
}

// ---------------------------------------------------------------------------
// batched transpose + convert: in fp32 [batch][R][C] -> out fp16 [batch][Cpad][R]
// (rows C..Cpad-1 of output zero-filled). R % 32 == 0 required.
__global__ void transpose_cvt(const float* __restrict__ in, unsigned short* __restrict__ out,
                              int R, int C, int Cpad) {
  __shared__ float tile[32][33];
  int b = blockIdx.z;
  const float* ib = in + (size_t)b * R * C;
  unsigned short* ob = out + (size_t)b * Cpad * R;
  int c0 = blockIdx.x * 32, r0 = blockIdx.y * 32;
  int tx = threadIdx.x & 31, ty = threadIdx.x >> 5;
#pragma unroll
  for (int j = 0; j < 4; ++j) {
    int r = r0 + ty + j * 8, c = c0 + tx;
    tile[ty + j * 8][tx] = (c < C) ? ib[(size_t)r * C + c] : 0.0f;
  }
  __syncthreads();
#pragma unroll
  for (int j = 0; j < 4; ++j) {
    int orow = c0 + ty + j * 8, ocol = r0 + tx;
    if (orow < Cpad) ob[(size_t)orow * R + ocol] = f2h(tile[tx][ty + j * 8]);
  }
}

// ---------------------------------------------------------------------------
// mean over ensemble: out[i] = (1/KE) * sum_k L[k*sk + i], i in [0, n)
__global__ void reduce_mean(const float* __restrict__ L, float* __restrict__ out,
                            int n, long long sk) {
  int i = blockIdx.x * 256 + threadIdx.x;
  if (i < n) {
    float s = 0.f;
#pragma unroll
    for (int k = 0; k < KE; ++k) s += L[(long long)k * sk + i];
    out[i] = s * (1.0f / (float)KE);
  }
}

// ---------------------------------------------------------------------------
// Batched GEMM (grid.z = ensemble member k):
//   C[k] = act(A[k] [M x KD] row-major  @  Bt[k]^T  + bias[k])
// Bt is [Ntiles*128][KD] row-major (N-major transposed weights): both A and B
// fragments are k-contiguous -> ds_read_b128.
// Tile 128x128, 256 threads (4 waves 2x2), wave does 4x4 of 16x16x32 MFMA.
// BK=64: 32 MFMAs per barrier-pair (2x the drain amortization of BK=32),
// 8 global_load_lds in flight per burst. Fragments loaded per K-half to keep
// register peak ~= BK=32 level (3 blocks/CU).
// LDS row = 64 shorts = 128 B; 16B chunk g XOR-swizzled with (row&7) ->
// frag ds_read_b128 lands 2-way on banks (free).
template <int RELU, int FINAL, int KD>
__global__ __launch_bounds__(256) void gemm_f16(
    const unsigned short* __restrict__ A, long long sAk,
    const unsigned short* __restrict__ Bt, long long sBk,
    const float* __restrict__ bias, int sBiasK,
    unsigned short* __restrict__ Out, long long sOutK,
    float* __restrict__ OutF, long long sFk) {
  const int t = threadIdx.x;
  const int lane = t & 63;
  const int wave = t >> 6;
  const int wm = wave & 1;
  const int wn = wave >> 1;
  const int kz = blockIdx.z;
  const int m0 = blockIdx.y * 128;
  const int n0 = blockIdx.x * 128;

  const unsigned short* Ab = A + (long long)kz * sAk + (long long)m0 * KD;
  const unsigned short* Bb = Bt + (long long)kz * sBk + (long long)n0 * KD;

  __shared__ __align__(16) unsigned short smA[128 * 64];  // 16 KB
  __shared__ __align__(16) unsigned short smB[128 * 64];  // 16 KB

  float4_t acc[4][4];
#pragma unroll
  for (int i = 0; i < 4; ++i)
#pragma unroll
    for (int j = 0; j < 4; ++j) acc[i][j] = (float4_t){0.f, 0.f, 0.f, 0.f};

  // staging: per operand 1024 16B-slots (128 rows x 8 chunks); thread t owns
  // slots j*256+t. slot s -> row s>>3, physical chunk p=s&7 holds logical
  // chunk g = p ^ (row&7).
  const unsigned short* ga[4];
  const unsigned short* gb[4];
  unsigned short* la[4];
  unsigned short* lb[4];
#pragma unroll
  for (int j = 0; j < 4; ++j) {
    int s = j * 256 + t;
    int row = s >> 3;
    int g = (s & 7) ^ (row & 7);
    ga[j] = Ab + (long long)row * KD + g * 8;
    gb[j] = Bb + (long long)row * KD + g * 8;
    la[j] = smA + (size_t)((j * 256 + (t & 0xC0)) * 8);
    lb[j] = smB + (size_t)((j * 256 + (t & 0xC0)) * 8);
  }

  const int r16 = lane & 15;
  const int q = lane >> 4;
  // fragment LDS offsets (shorts), invariant across K-steps
  int offA[4][2], offB[4][2];
#pragma unroll
  for (int i = 0; i < 4; ++i) {
#pragma unroll
    for (int kh = 0; kh < 2; ++kh) {
      int ra = wm * 64 + i * 16 + r16;
      offA[i][kh] = ra * 64 + ((((kh * 4 + q)) ^ (ra & 7)) << 3);
      int rb = wn * 64 + i * 16 + r16;
      offB[i][kh] = rb * 64 + ((((kh * 4 + q)) ^ (rb & 7)) << 3);
    }
  }

#pragma unroll
  for (int kt = 0; kt < KD; kt += 64) {
#pragma unroll
    for (int j = 0; j < 4; ++j) gll16(ga[j] + kt, la[j]);
#pragma unroll
    for (int j = 0; j < 4; ++j) gll16(gb[j] + kt, lb[j]);
    __syncthreads();  // drains vmcnt; LDS tile valid

#pragma unroll
    for (int kh = 0; kh < 2; ++kh) {
      short8 af[4], bf[4];
#pragma unroll
      for (int i = 0; i < 4; ++i) af[i] = *(const short8*)(smA + offA[i][kh]);
#pragma unroll
      for (int i = 0; i < 4; ++i) bf[i] = *(const short8*)(smB + offB[i][kh]);
#pragma unroll
      for (int mi = 0; mi < 4; ++mi)
#pragma unroll
        for (int ni = 0; ni < 4; ++ni)
          acc[mi][ni] = __builtin_amdgcn_mfma_f32_16x16x32_f16(af[mi], bf[ni], acc[mi][ni], 0, 0, 0);
    }
    __syncthreads();  // protect LDS from next iteration's staging
  }

  // epilogue: C/D layout col = lane&15, row = (lane>>4)*4 + reg  [m89-verified]
  const int rbase = q * 4;
  if (FINAL) {
    // per-k fp32 logits into OutF[kz*sFk + m*CC + n]; mean applied by reduce_mean
#pragma unroll
    for (int ni = 0; ni < 4; ++ni) {
      int n = wn * 64 + ni * 16 + r16;  // n0 == 0 for final layer
      if (n < CC) {
        float bv = bias[kz * sBiasK + n];
#pragma unroll
        for (int mi = 0; mi < 4; ++mi) {
#pragma unroll
          for (int r = 0; r < 4; ++r) {
            int m = m0 + wm * 64 + mi * 16 + rbase + r;
            OutF[(long long)kz * sFk + (long long)m * CC + n] = acc[mi][ni][r] + bv;
          }
        }
      }
    }
  } else {
#pragma unroll
    for (int ni = 0; ni < 4; ++ni) {
      int n = n0 + wn * 64 + ni * 16 + r16;
      float bv = bias[kz * sBiasK + n];
#pragma unroll
      for (int mi = 0; mi < 4; ++mi) {
        int m = m0 + wm * 64 + mi * 16 + rbase;
        unsigned short* op = Out + (long long)kz * sOutK + (long long)m * HH + n;
#pragma unroll
        for (int r = 0; r < 4; ++r) {
          float v = acc[mi][ni][r] + bv;
          if (RELU) v = fmaxf(v, 0.f);
          op[(long long)r * HH] = f2h(v);
        }
      }
    }
  }
}

// ---------------------------------------------------------------------------
extern "C" void kernel_launch(void* const* d_in, const int* in_sizes, int n_in,
                              void* d_out, int out_size, void* d_ws, size_t ws_size,
                              hipStream_t stream) {
  (void)in_sizes; (void)n_in; (void)out_size;
  const float* x     = (const float*)d_in[0];
  const float* W_in  = (const float*)d_in[1];
  const float* b_in  = (const float*)d_in[2];
  const float* W_hid = (const float*)d_in[3];
  const float* b_hid = (const float*)d_in[4];
  const float* W_out = (const float*)d_in[5];
  const float* b_out = (const float*)d_in[6];
  float* out = (float*)d_out;

  char* ws = (char*)d_ws;
  size_t off = 0;
  auto alloc = [&](size_t bytes) -> void* {
    void* p = ws + off;
    off += (bytes + 255) & ~(size_t)255;
    return p;
  };
  unsigned short* xb    = (unsigned short*)alloc((size_t)BB * FF * 2);
  unsigned short* WinT  = (unsigned short*)alloc((size_t)KE * HH * FF * 2);
  unsigned short* WhidT = (unsigned short*)alloc((size_t)NHIDL * KE * HH * HH * 2);
  unsigned short* WoutT = (unsigned short*)alloc((size_t)KE * CPAD * HH * 2);
  size_t fixed = off;

  int Bc = BB;  // batch chunk; shrink if workspace is small
  while (Bc > 128 && fixed + 2 * (size_t)KE * Bc * HH * 2 > ws_size) Bc >>= 1;
  unsigned short* h0 = (unsigned short*)alloc((size_t)KE * Bc * HH * 2);
  unsigned short* h1 = (unsigned short*)alloc((size_t)KE * Bc * HH * 2);

  // conversions / weight transposes (fp32 -> fp16, W stored N-major)
  cvt_f16<<<(BB * FF / 4 + 255) / 256, 256, 0, stream>>>(x, xb, BB * FF / 4);
  transpose_cvt<<<dim3(HH / 32, FF / 32, KE), 256, 0, stream>>>(W_in, WinT, FF, HH, HH);
  transpose_cvt<<<dim3(HH / 32, HH / 32, NHIDL * KE), 256, 0, stream>>>(W_hid, WhidT, HH, HH, HH);
  transpose_cvt<<<dim3(CPAD / 32, HH / 32, KE), 256, 0, stream>>>(W_out, WoutT, HH, CC, CPAD);

  for (int c0 = 0; c0 < BB; c0 += Bc) {
    // layer 0: [Bc,F] @ [F,H] (A shared across k -> stride 0)
    gemm_f16<1, 0, FF><<<dim3(HH / 128, Bc / 128, KE), 256, 0, stream>>>(
        xb + (size_t)c0 * FF, 0LL, WinT, (long long)HH * FF, b_in, HH,
        h0, (long long)Bc * HH, nullptr, 0LL);
    unsigned short* hin = h0;
    unsigned short* hout = h1;
    for (int l = 0; l < NHIDL; ++l) {
      gemm_f16<1, 0, HH><<<dim3(HH / 128, Bc / 128, KE), 256, 0, stream>>>(
          hin, (long long)Bc * HH, WhidT + (size_t)l * KE * HH * HH, (long long)HH * HH,
          b_hid + (size_t)l * KE * HH, HH, hout, (long long)Bc * HH, nullptr, 0LL);
      unsigned short* tmp = hin; hin = hout; hout = tmp;
    }
    // output layer: per-k fp32 logits into the dead h-buffer (hout), then mean
    float* Lbuf = (float*)hout;  // KE*Bc*CC*4 <= KE*Bc*HH*2 always
    gemm_f16<0, 1, HH><<<dim3(1, Bc / 128, KE), 256, 0, stream>>>(
        hin, (long long)Bc * HH, WoutT, (long long)CPAD * HH, b_out, CC,
        nullptr, 0LL, Lbuf, (long long)Bc * CC);
    reduce_mean<<<(Bc * CC + 255) / 256, 256, 0, stream>>>(
        Lbuf, out + (size_t)c0 * CC, Bc * CC, (long long)Bc * CC);
  }
}

// Round 3
// 1949.192 us; speedup vs baseline: 1.1727x; 1.0228x over previous
//
#include <hip/hip_runtime.h>
#include <stdint.h>

// Problem dims (TabM packed ensemble)
#define BB   4096
#define FF   512
#define HH   1024
#define CC   100
#define KE   32
#define NHIDL 3
#define CPAD 128   // W_out N padded to 128 (rows 100..127 zeroed)

typedef __attribute__((ext_vector_type(8))) short short8;   // 8 x fp16 = 4 VGPRs
typedef __attribute__((ext_vector_type(4))) float float4_t; // MFMA accumulator

// fp32 -> fp16 (RNE via hardware cvt)
__device__ __forceinline__ unsigned short f2h(float f) {
  _Float16 h = (_Float16)f;
  union { _Float16 h; unsigned short u; } cv;
  cv.h = h;
  return cv.u;
}

// async global->LDS, 16B per lane. LDS dest is wave-uniform base + lane*16.
__device__ __forceinline__ void gll16(const void* g, void* l) {
  __builtin_amdgcn_global_load_lds((const __attribute__((address_space(1))) void*)g,
                                   (__attribute__((address_space(3))) void*)l,
                                   16, 0, 0);
}

// ---------------------------------------------------------------------------
// elementwise fp32 -> fp16 convert (x)
__global__ void cvt_f16(const float* __restrict__ in, unsigned short* __restrict__ out, int n4) {
  int i = blockIdx.x * 256 + threadIdx.x;
  if (i < n4) {
    float4 v = ((const float4*)in)[i];
    ushort4 o;
    o.x = f2h(v.x); o.y = f2h(v.y); o.z = f2h(v.z); o.w = f2h(v.w);
    ((ushort4*)out)[i] = o;
  }
}

// ---------------------------------------------------------------------------
// batched transpose + convert: in fp32 [batch][R][C] -> out fp16 [batch][Cpad][R]
// (rows C..Cpad-1 of output zero-filled). R % 32 == 0 required.
__global__ void transpose_cvt(const float* __restrict__ in, unsigned short* __restrict__ out,
                              int R, int C, int Cpad) {
  __shared__ float tile[32][33];
  int b = blockIdx.z;
  const float* ib = in + (size_t)b * R * C;
  unsigned short* ob = out + (size_t)b * Cpad * R;
  int c0 = blockIdx.x * 32, r0 = blockIdx.y * 32;
  int tx = threadIdx.x & 31, ty = threadIdx.x >> 5;
#pragma unroll
  for (int j = 0; j < 4; ++j) {
    int r = r0 + ty + j * 8, c = c0 + tx;
    tile[ty + j * 8][tx] = (c < C) ? ib[(size_t)r * C + c] : 0.0f;
  }
  __syncthreads();
#pragma unroll
  for (int j = 0; j < 4; ++j) {
    int orow = c0 + ty + j * 8, ocol = r0 + tx;
    if (orow < Cpad) ob[(size_t)orow * R + ocol] = f2h(tile[tx][ty + j * 8]);
  }
}

// ---------------------------------------------------------------------------
// mean over ensemble: out[i] = (1/KE) * sum_k L[k*sk + i], i in [0, n)
__global__ void reduce_mean(const float* __restrict__ L, float* __restrict__ out,
                            int n, long long sk) {
  int i = blockIdx.x * 256 + threadIdx.x;
  if (i < n) {
    float s = 0.f;
#pragma unroll
    for (int k = 0; k < KE; ++k) s += L[(long long)k * sk + i];
    out[i] = s * (1.0f / (float)KE);
  }
}

// ---------------------------------------------------------------------------
// Batched GEMM (grid.z = ensemble member k):
//   C[k] = act(A[k] [M x KD] row-major  @  Bt[k]^T  + bias[k])
// Bt is [Ntiles*128][KD] row-major (N-major transposed weights): both A and B
// fragments are k-contiguous -> ds_read_b128.
// Tile 128x128, 256 threads (4 waves 2x2), wave does 4x4 of 16x16x32 MFMA.
// BK=64: 32 MFMAs per barrier-pair, 8 global_load_lds in flight per burst.
// LDS row = 64 shorts = 128 B; 16B chunk g XOR-swizzled with (row&7) ->
// frag ds_read_b128 lands 2-way on banks (free).
// __launch_bounds__(256,4): cap unified VGPR+AGPR at 128 -> 4 blocks/CU
// (16 waves) for cross-block phase overlap. Staging addresses carried as 4
// shared 32-bit element offsets (A/B reuse them) instead of 8 pointer pairs
// to fit the cap.
template <int RELU, int FINAL, int KD>
__global__ __launch_bounds__(256, 4) void gemm_f16(
    const unsigned short* __restrict__ A, long long sAk,
    const unsigned short* __restrict__ Bt, long long sBk,
    const float* __restrict__ bias, int sBiasK,
    unsigned short* __restrict__ Out, long long sOutK,
    float* __restrict__ OutF, long long sFk) {
  const int t = threadIdx.x;
  const int lane = t & 63;
  const int wave = t >> 6;
  const int wm = wave & 1;
  const int wn = wave >> 1;
  const int kz = blockIdx.z;
  const int m0 = blockIdx.y * 128;
  const int n0 = blockIdx.x * 128;

  const unsigned short* Ab = A + (long long)kz * sAk + (long long)m0 * KD;
  const unsigned short* Bb = Bt + (long long)kz * sBk + (long long)n0 * KD;

  __shared__ __align__(16) unsigned short smA[128 * 64];  // 16 KB
  __shared__ __align__(16) unsigned short smB[128 * 64];  // 16 KB

  float4_t acc[4][4];
#pragma unroll
  for (int i = 0; i < 4; ++i)
#pragma unroll
    for (int j = 0; j < 4; ++j) acc[i][j] = (float4_t){0.f, 0.f, 0.f, 0.f};

  // staging: per operand 1024 16B-slots (128 rows x 8 chunks); thread t owns
  // slots j*256+t. slot s -> row s>>3, physical chunk p=s&7 holds logical
  // chunk g = p ^ (row&7). Same element offset serves A and B.
  int goff[4];
  unsigned short* la[4];
  unsigned short* lb[4];
#pragma unroll
  for (int j = 0; j < 4; ++j) {
    int s = j * 256 + t;
    int row = s >> 3;
    int g = (s & 7) ^ (row & 7);
    goff[j] = row * KD + g * 8;                       // element offset, 32-bit
    la[j] = smA + (size_t)((j * 256 + (t & 0xC0)) * 8);  // wave-uniform
    lb[j] = smB + (size_t)((j * 256 + (t & 0xC0)) * 8);
  }

  const int r16 = lane & 15;
  const int q = lane >> 4;
  // fragment LDS offsets (shorts), invariant across K-steps
  int offA[4][2], offB[4][2];
#pragma unroll
  for (int i = 0; i < 4; ++i) {
#pragma unroll
    for (int kh = 0; kh < 2; ++kh) {
      int ra = wm * 64 + i * 16 + r16;
      offA[i][kh] = ra * 64 + ((((kh * 4 + q)) ^ (ra & 7)) << 3);
      int rb = wn * 64 + i * 16 + r16;
      offB[i][kh] = rb * 64 + ((((kh * 4 + q)) ^ (rb & 7)) << 3);
    }
  }

#pragma unroll
  for (int kt = 0; kt < KD; kt += 64) {
#pragma unroll
    for (int j = 0; j < 4; ++j) gll16(Ab + goff[j] + kt, la[j]);
#pragma unroll
    for (int j = 0; j < 4; ++j) gll16(Bb + goff[j] + kt, lb[j]);
    __syncthreads();  // drains vmcnt; LDS tile valid

#pragma unroll
    for (int kh = 0; kh < 2; ++kh) {
      short8 af[4], bf[4];
#pragma unroll
      for (int i = 0; i < 4; ++i) af[i] = *(const short8*)(smA + offA[i][kh]);
#pragma unroll
      for (int i = 0; i < 4; ++i) bf[i] = *(const short8*)(smB + offB[i][kh]);
#pragma unroll
      for (int mi = 0; mi < 4; ++mi)
#pragma unroll
        for (int ni = 0; ni < 4; ++ni)
          acc[mi][ni] = __builtin_amdgcn_mfma_f32_16x16x32_f16(af[mi], bf[ni], acc[mi][ni], 0, 0, 0);
    }
    __syncthreads();  // protect LDS from next iteration's staging
  }

  // epilogue: C/D layout col = lane&15, row = (lane>>4)*4 + reg  [m89-verified]
  const int rbase = q * 4;
  if (FINAL) {
    // per-k fp32 logits into OutF[kz*sFk + m*CC + n]; mean applied by reduce_mean
#pragma unroll
    for (int ni = 0; ni < 4; ++ni) {
      int n = wn * 64 + ni * 16 + r16;  // n0 == 0 for final layer
      if (n < CC) {
        float bv = bias[kz * sBiasK + n];
#pragma unroll
        for (int mi = 0; mi < 4; ++mi) {
#pragma unroll
          for (int r = 0; r < 4; ++r) {
            int m = m0 + wm * 64 + mi * 16 + rbase + r;
            OutF[(long long)kz * sFk + (long long)m * CC + n] = acc[mi][ni][r] + bv;
          }
        }
      }
    }
  } else {
#pragma unroll
    for (int ni = 0; ni < 4; ++ni) {
      int n = n0 + wn * 64 + ni * 16 + r16;
      float bv = bias[kz * sBiasK + n];
#pragma unroll
      for (int mi = 0; mi < 4; ++mi) {
        int m = m0 + wm * 64 + mi * 16 + rbase;
        unsigned short* op = Out + (long long)kz * sOutK + (long long)m * HH + n;
#pragma unroll
        for (int r = 0; r < 4; ++r) {
          float v = acc[mi][ni][r] + bv;
          if (RELU) v = fmaxf(v, 0.f);
          op[(long long)r * HH] = f2h(v);
        }
      }
    }
  }
}

// ---------------------------------------------------------------------------
extern "C" void kernel_launch(void* const* d_in, const int* in_sizes, int n_in,
                              void* d_out, int out_size, void* d_ws, size_t ws_size,
                              hipStream_t stream) {
  (void)in_sizes; (void)n_in; (void)out_size;
  const float* x     = (const float*)d_in[0];
  const float* W_in  = (const float*)d_in[1];
  const float* b_in  = (const float*)d_in[2];
  const float* W_hid = (const float*)d_in[3];
  const float* b_hid = (const float*)d_in[4];
  const float* W_out = (const float*)d_in[5];
  const float* b_out = (const float*)d_in[6];
  float* out = (float*)d_out;

  char* ws = (char*)d_ws;
  size_t off = 0;
  auto alloc = [&](size_t bytes) -> void* {
    void* p = ws + off;
    off += (bytes + 255) & ~(size_t)255;
    return p;
  };
  unsigned short* xb    = (unsigned short*)alloc((size_t)BB * FF * 2);
  unsigned short* WinT  = (unsigned short*)alloc((size_t)KE * HH * FF * 2);
  unsigned short* WhidT = (unsigned short*)alloc((size_t)NHIDL * KE * HH * HH * 2);
  unsigned short* WoutT = (unsigned short*)alloc((size_t)KE * CPAD * HH * 2);
  size_t fixed = off;

  int Bc = BB;  // batch chunk; shrink if workspace is small
  while (Bc > 128 && fixed + 2 * (size_t)KE * Bc * HH * 2 > ws_size) Bc >>= 1;
  unsigned short* h0 = (unsigned short*)alloc((size_t)KE * Bc * HH * 2);
  unsigned short* h1 = (unsigned short*)alloc((size_t)KE * Bc * HH * 2);

  // conversions / weight transposes (fp32 -> fp16, W stored N-major)
  cvt_f16<<<(BB * FF / 4 + 255) / 256, 256, 0, stream>>>(x, xb, BB * FF / 4);
  transpose_cvt<<<dim3(HH / 32, FF / 32, KE), 256, 0, stream>>>(W_in, WinT, FF, HH, HH);
  transpose_cvt<<<dim3(HH / 32, HH / 32, NHIDL * KE), 256, 0, stream>>>(W_hid, WhidT, HH, HH, HH);
  transpose_cvt<<<dim3(CPAD / 32, HH / 32, KE), 256, 0, stream>>>(W_out, WoutT, HH, CC, CPAD);

  for (int c0 = 0; c0 < BB; c0 += Bc) {
    // layer 0: [Bc,F] @ [F,H] (A shared across k -> stride 0)
    gemm_f16<1, 0, FF><<<dim3(HH / 128, Bc / 128, KE), 256, 0, stream>>>(
        xb + (size_t)c0 * FF, 0LL, WinT, (long long)HH * FF, b_in, HH,
        h0, (long long)Bc * HH, nullptr, 0LL);
    unsigned short* hin = h0;
    unsigned short* hout = h1;
    for (int l = 0; l < NHIDL; ++l) {
      gemm_f16<1, 0, HH><<<dim3(HH / 128, Bc / 128, KE), 256, 0, stream>>>(
          hin, (long long)Bc * HH, WhidT + (size_t)l * KE * HH * HH, (long long)HH * HH,
          b_hid + (size_t)l * KE * HH, HH, hout, (long long)Bc * HH, nullptr, 0LL);
      unsigned short* tmp = hin; hin = hout; hout = tmp;
    }
    // output layer: per-k fp32 logits into the dead h-buffer (hout), then mean
    float* Lbuf = (float*)hout;  // KE*Bc*CC*4 <= KE*Bc*HH*2 always
    gemm_f16<0, 1, HH><<<dim3(1, Bc / 128, KE), 256, 0, stream>>>(
        hin, (long long)Bc * HH, WoutT, (long long)CPAD * HH, b_out, CC,
        nullptr, 0LL, Lbuf, (long long)Bc * CC);
    reduce_mean<<<(Bc * CC + 255) / 256, 256, 0, stream>>>(
        Lbuf, out + (size_t)c0 * CC, Bc * CC, (long long)Bc * CC);
  }
}